// Round 6
// baseline (142.153 us; speedup 1.0000x reference)
//
#include <hip/hip_runtime.h>
#include <math.h>

#define B 1024
#define C 100000
#define D 64
#define TC 128                  // classes per chunk
#define NCH 782                 // ceil(C/TC); NCH*TC = 100096
#define NPADROWS (NCH * TC)
#define CPAD (NPADROWS - C)     // 96 zero pad rows
#define L2E 1.4426950408889634f

typedef __attribute__((ext_vector_type(8))) short short8;
typedef __attribute__((ext_vector_type(4))) float f32x4;

// ws byte layout:
//   WS_PART (3.2 MB)  : s-partials float [chunk][row]
//   WS_CW2  (4 KB)    : cw2[row] = -2*||x_row||*log2e
//   WS_XBF  (128 KB)  : xs as bf16 [B][64]
//   WS_PBF  (12.8 MB) : normalized proxies bf16 [NPADROWS][64] (pad rows 0)
//   WS_RSUM (4 KB)    : rowsum[row]
#define WS_PART 0
#define WS_CW2  ((size_t)NCH * B * 4)
#define WS_XBF  (WS_CW2 + B * 4)
#define WS_PBF  (WS_XBF + (size_t)B * D * 2)
#define WS_RSUM (WS_PBF + (size_t)NPADROWS * D * 2)

#define GLB(p) ((const __attribute__((address_space(1))) void*)(p))
#define LDS(p) ((__attribute__((address_space(3))) void*)(p))

static __device__ __forceinline__ unsigned short f2bf(float f) {
    unsigned u = __float_as_uint(f);
    return (unsigned short)((u + 0x7fffu + ((u >> 16) & 1u)) >> 16);  // RNE
}
static __device__ __forceinline__ float bf_round(float f) {
    return __uint_as_float(((unsigned)f2bf(f)) << 16);
}
static __device__ __forceinline__ float fexp2(float x) {
#if __has_builtin(__builtin_amdgcn_exp2f)
    return __builtin_amdgcn_exp2f(x);
#else
    return __expf(x * 0.6931471805599453f);
#endif
}

// ---- prep: proxies -> normalized bf16 Pbf (pad rows 0); xs -> bf16 + cw2 ----
__global__ __launch_bounds__(256) void proxynca_prep(
    const float* __restrict__ xs, const float* __restrict__ proxies,
    unsigned short* __restrict__ Xbf, unsigned short* __restrict__ Pbf,
    float* __restrict__ cw2)
{
    const int t = threadIdx.x;
    const int rl = t >> 4, f4 = t & 15;
    const int bb = blockIdx.x;
    if (bb < NPADROWS / 16) {
        int gr = bb * 16 + rl;
        float4 v = make_float4(0.f, 0.f, 0.f, 0.f);
        if (gr < C) v = *(const float4*)(proxies + (size_t)gr * D + f4 * 4);
        float ss = v.x*v.x + v.y*v.y + v.z*v.z + v.w*v.w;
        ss += __shfl_xor(ss, 1); ss += __shfl_xor(ss, 2);
        ss += __shfl_xor(ss, 4); ss += __shfl_xor(ss, 8);
        float rn = 1.0f / fmaxf(sqrtf(ss), 1e-12f);
        ushort4 w;
        w.x = f2bf(v.x * rn); w.y = f2bf(v.y * rn);
        w.z = f2bf(v.z * rn); w.w = f2bf(v.w * rn);
        *(ushort4*)(Pbf + (size_t)gr * D + f4 * 4) = w;
    } else {
        int row = (bb - NPADROWS / 16) * 16 + rl;
        const float4 v = *(const float4*)(xs + (size_t)row * D + f4 * 4);
        float ss = v.x*v.x + v.y*v.y + v.z*v.z + v.w*v.w;
        ss += __shfl_xor(ss, 1); ss += __shfl_xor(ss, 2);
        ss += __shfl_xor(ss, 4); ss += __shfl_xor(ss, 8);
        ushort4 w;
        w.x = f2bf(v.x); w.y = f2bf(v.y); w.z = f2bf(v.z); w.w = f2bf(v.w);
        *(ushort4*)(Xbf + (size_t)row * D + f4 * 4) = w;
        if (f4 == 0) cw2[row] = -2.0f * sqrtf(ss) * L2E;
    }
}

// ---- main: 256 rows x 128 classes; all-DMA staging, MFMA + exp2 epilogue ----
__global__ __launch_bounds__(512, 3) void proxynca_main(
    const unsigned short* __restrict__ Pbf, const unsigned short* __restrict__ Xbf,
    const float* __restrict__ cw2v, float* __restrict__ partial)
{
    __shared__ __align__(16) unsigned short Ash[256 * 64];   // 32 KB, swizzled
    __shared__ __align__(16) unsigned short Bsh[TC * 64];    // 16 KB; reused as scratch
    __shared__ float crow[256];

    const int t = threadIdx.x;                 // 0..511
    const int lane = t & 63;
    const int wv = t >> 6;                     // 0..7
    const int rg = blockIdx.x;                 // 0..3
    const int ct = blockIdx.y;                 // 0..781
    const int rbase = rg * 256;

    // stage A (256 rows of Xbf) via DMA, source-XOR-swizzled:
    // LDS chunk (row,p) holds global chunk (row, p^(row&7))
    const unsigned short* Asrc = Xbf + (size_t)rbase * D;
    #pragma unroll
    for (int j = 0; j < 4; ++j) {
        int c = (j * 8 + wv) * 64 + lane;
        int row = c >> 3, p = c & 7;
        int sc = (row << 3) | (p ^ (row & 7));
        __builtin_amdgcn_global_load_lds(GLB(Asrc + sc * 8),
            LDS(Ash + (size_t)(j * 8 + wv) * 512), 16, 0, 0);
    }
    // stage B (128 normalized proxy rows) via DMA, same swizzle
    const unsigned short* Bsrc = Pbf + (size_t)ct * TC * D;
    #pragma unroll
    for (int j = 0; j < 2; ++j) {
        int c = (j * 8 + wv) * 64 + lane;
        int row = c >> 3, p = c & 7;
        int sc = (row << 3) | (p ^ (row & 7));
        __builtin_amdgcn_global_load_lds(GLB(Bsrc + sc * 8),
            LDS(Bsh + (size_t)(j * 8 + wv) * 512), 16, 0, 0);
    }
    if (t < 256) crow[t] = cw2v[rbase + t];
    __syncthreads();                            // DMA + crow visible

    const int quad = lane >> 4, sixt = lane & 15;
    const int mg = wv >> 1;                     // 0..3 : 64-row group
    const int ng = wv & 1;                      // 0..1 : 64-class group

    short8 bfr[4][2];
    #pragma unroll
    for (int ns = 0; ns < 4; ++ns) {
        int cl = ng * 64 + ns * 16 + sixt;
        int sw = cl & 7;
        bfr[ns][0] = *(const short8*)(Bsh + (size_t)(((cl << 3) | (quad ^ sw)) * 8));
        bfr[ns][1] = *(const short8*)(Bsh + (size_t)(((cl << 3) | ((4 + quad) ^ sw)) * 8));
    }
    short8 af[4][2];
    #pragma unroll
    for (int ms = 0; ms < 4; ++ms) {
        int rowL = mg * 64 + ms * 16 + sixt;
        int sw = rowL & 7;
        af[ms][0] = *(const short8*)(Ash + (size_t)(((rowL << 3) | (quad ^ sw)) * 8));
        af[ms][1] = *(const short8*)(Ash + (size_t)(((rowL << 3) | ((4 + quad) ^ sw)) * 8));
    }
    __syncthreads();                            // all B fragments in regs; Bsh free

    float cw[4][4];
    #pragma unroll
    for (int ms = 0; ms < 4; ++ms)
        #pragma unroll
        for (int rgi = 0; rgi < 4; ++rgi)
            cw[ms][rgi] = crow[mg * 64 + ms * 16 + quad * 4 + rgi];

    float s_acc[4][4];
    #pragma unroll
    for (int ms = 0; ms < 4; ++ms)
        #pragma unroll
        for (int rgi = 0; rgi < 4; ++rgi) s_acc[ms][rgi] = 0.f;

    #pragma unroll
    for (int ns = 0; ns < 4; ++ns)
        #pragma unroll
        for (int ms = 0; ms < 4; ++ms) {
            f32x4 acc = {0.f, 0.f, 0.f, 0.f};
            acc = __builtin_amdgcn_mfma_f32_16x16x32_bf16(af[ms][0], bfr[ns][0], acc, 0, 0, 0);
            acc = __builtin_amdgcn_mfma_f32_16x16x32_bf16(af[ms][1], bfr[ns][1], acc, 0, 0, 0);
            #pragma unroll
            for (int rgi = 0; rgi < 4; ++rgi)
                s_acc[ms][rgi] += fexp2(fmaf(2.0f * L2E, acc[rgi], cw[ms][rgi]));
        }

    // one pair-combine step, then per-lane partials into scratch (= Bsh memory)
    float (*scratch)[16] = (float(*)[16])Bsh;   // 256 rows x 16 slots = 16 KB
    #pragma unroll
    for (int ms = 0; ms < 4; ++ms)
        #pragma unroll
        for (int rgi = 0; rgi < 4; ++rgi) {
            float s = s_acc[ms][rgi] + __shfl_xor(s_acc[ms][rgi], 1);
            if ((sixt & 1) == 0)
                scratch[mg * 64 + ms * 16 + quad * 4 + rgi][ng * 8 + (sixt >> 1)] = s;
        }
    __syncthreads();
    if (t < 256) {
        const float* r = scratch[t];
        float4 a = *(const float4*)(r);
        float4 b = *(const float4*)(r + 4);
        float4 c = *(const float4*)(r + 8);
        float4 d = *(const float4*)(r + 12);
        float s = ((a.x + a.y) + (a.z + a.w)) + ((b.x + b.y) + (b.z + b.w))
                + ((c.x + c.y) + (c.z + c.w)) + ((d.x + d.y) + (d.z + d.w));
        partial[(size_t)ct * B + rbase + t] = s;   // coalesced 1 KB burst
    }
}

// ---- sumk: coalesced per-row sum over all chunks ----
__global__ __launch_bounds__(256) void proxynca_sumk(
    const float* __restrict__ partial, float* __restrict__ rowsum)
{
    __shared__ float red[32][8];
    const int t = threadIdx.x;
    const int rl = t & 31;                 // row within block
    const int pp = t >> 5;                 // chunk-stripe 0..7
    const int row = blockIdx.x * 32 + rl;
    float s = 0.f;
    for (int j = pp; j < NCH; j += 8)
        s += partial[(size_t)j * B + row];  // lanes read consecutive rows
    red[rl][pp] = s;
    __syncthreads();
    if (t < 32) {
        const float* r = red[t];
        rowsum[blockIdx.x * 32 + t] =
            ((r[0] + r[1]) + (r[2] + r[3])) + ((r[4] + r[5]) + (r[6] + r[7]));
    }
}

// ---- per-row epilogue + mean (atomicAdd into zeroed d_out) ----
__global__ __launch_bounds__(256) void proxynca_reduce(
    const float* __restrict__ xs, const int* __restrict__ ys,
    const float* __restrict__ proxies, const float* __restrict__ rowsum,
    float* __restrict__ out)
{
    __shared__ float acc4[4];
    const int lane = threadIdx.x & 63;
    const int w = threadIdx.x >> 6;
    const int row = blockIdx.x * 4 + w;

    float x = xs[(size_t)row * D + lane];
    int y = ys[row];
    float p = proxies[(size_t)y * D + lane];

    float xx = x * x, pp = p * p;
    #pragma unroll
    for (int off = 1; off < 64; off <<= 1) {
        xx += __shfl_xor(xx, off);
        pp += __shfl_xor(pp, off);
    }
    float nx = sqrtf(xx);
    float rn = 1.0f / fmaxf(sqrtf(pp), 1e-12f);
    float ph = p * rn;

    float xp = x * ph;                       // exact fp32 dot for d_pos
    float xpb = bf_round(x) * bf_round(ph);  // bf16-matched dot for s subtraction
    #pragma unroll
    for (int off = 1; off < 64; off <<= 1) {
        xp  += __shfl_xor(xp, off);
        xpb += __shfl_xor(xpb, off);
    }

    if (lane == 0) {
        float s = rowsum[row];
        float cw2r = -2.0f * nx * L2E;
        float e_pos = fexp2(fmaf(2.0f * L2E, xpb, cw2r));   // positive class term
        float e_pad = fexp2(cw2r);                          // each zero pad row
        float s_neg = s - e_pos - (float)CPAD * e_pad;
        acc4[w] = 2.0f * (nx - xp) + logf(s_neg);
    }
    __syncthreads();
    if (threadIdx.x == 0) {
        float v = acc4[0] + acc4[1] + acc4[2] + acc4[3];
        atomicAdd(out, v * (1.0f / (float)B));
    }
}

extern "C" void kernel_launch(void* const* d_in, const int* in_sizes, int n_in,
                              void* d_out, int out_size, void* d_ws, size_t ws_size,
                              hipStream_t stream)
{
    const float* xs      = (const float*)d_in[0];
    const int*   ys      = (const int*)d_in[1];
    const float* proxies = (const float*)d_in[2];
    char* ws = (char*)d_ws;
    float* partial = (float*)(ws + WS_PART);
    float* cw2     = (float*)(ws + WS_CW2);
    unsigned short* Xbf = (unsigned short*)(ws + WS_XBF);
    unsigned short* Pbf = (unsigned short*)(ws + WS_PBF);
    float* rowsum  = (float*)(ws + WS_RSUM);
    float* out = (float*)d_out;

    hipMemsetAsync(out, 0, sizeof(float), stream);
    proxynca_prep<<<NPADROWS / 16 + B / 16, 256, 0, stream>>>(xs, proxies, Xbf, Pbf, cw2);
    dim3 gridA(4, NCH);
    proxynca_main<<<gridA, 512, 0, stream>>>(Pbf, Xbf, cw2, partial);
    proxynca_sumk<<<B / 32, 256, 0, stream>>>(partial, rowsum);
    proxynca_reduce<<<B / 4, 256, 0, stream>>>(xs, ys, proxies, rowsum, out);
}